// Round 5
// baseline (478.682 us; speedup 1.0000x reference)
//
#include <hip/hip_runtime.h>

// Problem constants
#define DD 128    // nodes / input dim
#define HH 512    // hidden
#define NN 2048   // batch rows
#define NT 64     // rows per block tile
#define PLD 516   // pack LDS leading dim
#define PLD2 520  // h1s leading dim (bf16): row stride 1040B -> bank = 4*row mod 32

typedef __bf16 bf16x8 __attribute__((ext_vector_type(8)));
typedef __bf16 bf16x4 __attribute__((ext_vector_type(4)));
typedef float  floatx4  __attribute__((ext_vector_type(4)));
typedef float  floatx16 __attribute__((ext_vector_type(16)));

typedef const __attribute__((address_space(1))) void* as1cv;
typedef __attribute__((address_space(3))) void* as3v;

// ---------------------------------------------------------------------------
// x (fp32 row-major) -> xb (bf16 row-major). 2048x128, 16B/thread.
// ---------------------------------------------------------------------------
__global__ void cvt_x(const float* __restrict__ x, __bf16* __restrict__ xb) {
    int t = blockIdx.x * blockDim.x + threadIdx.x;
    float4 v = *(const float4*)(x + (size_t)t * 4);
    bf16x4 o;
    o[0] = (__bf16)v.x; o[1] = (__bf16)v.y; o[2] = (__bf16)v.z; o[3] = (__bf16)v.w;
    *(bf16x4*)(xb + (size_t)t * 4) = o;
}

// ---------------------------------------------------------------------------
// Pack W[d][K][H] fp32 -> bf16 32x32x16 A-fragment order via LDS transpose.
// Frag layout (A = W^T, m = H-col, k = K-row): lane l holds
//   A[ct*32 + (l&31)][ks*16 + (l>>5)*8 + j],  j = 0..7
//   Wp[((d*16 + ct)*nks16 + ks)*512 + l*8 + j] = W[d][ks*16+(l>>5)*8+j][ct*32+(l&31)]
// ---------------------------------------------------------------------------
__global__ void pack_w(const float* __restrict__ W, __bf16* __restrict__ Wp, int nks32) {
    __shared__ __bf16 Ls[32 * PLD];
    const int d  = blockIdx.x / nks32;
    const int ks = blockIdx.x % nks32;      // 32-row slab index
    const int tid = threadIdx.x;
    const int nks16 = nks32 * 2;
    const float* src = W + ((size_t)(d * nks32 + ks) * 32) * HH;

#pragma unroll
    for (int it = 0; it < 16; ++it) {
        int e = (it * 256 + tid) * 4;
        float4 v = *(const float4*)(src + e);
        bf16x4 o;
        o[0] = (__bf16)v.x; o[1] = (__bf16)v.y; o[2] = (__bf16)v.z; o[3] = (__bf16)v.w;
        *(bf16x4*)(Ls + (e >> 9) * PLD + (e & 511)) = o;
    }
    __syncthreads();

#pragma unroll
    for (int it = 0; it < 8; ++it) {
        int u  = it * 256 + tid;            // [0, 2048): 8-elem output units
        int l  = u & 63;
        int ct = (u >> 6) & 15;             // 32-col tile
        int kh = u >> 10;                   // k-substep within slab (0,1)
        int lr = l & 31, lh = l >> 5;
        bf16x8 v;
#pragma unroll
        for (int j = 0; j < 8; ++j)
            v[j] = Ls[(kh * 16 + lh * 8 + j) * PLD + ct * 32 + lr];
        *(bf16x8*)(Wp + ((size_t)(d * 16 + ct) * nks16 + (ks * 2 + kh)) * 512 + l * 8) = v;
    }
}

// ---------------------------------------------------------------------------
// Fused per-(d, row-tile) MLP, 32x32x16 MFMA, transposed operand order.
// Round 5: DEEP PREFETCH. Diagnosis across r0-r4: no pipe above ~35% busy
// (per-SIMD MFMA ~8%; "MfmaUtil 36%" is a CU-level OR) -> SIMDs idle in
// s_waitcnt on W-fragment loads (depth-1 prefetch can't cover 200-900 cyc
// L2/L3 latency) and same-iteration ds_reads. Fix: 4-slot register ring for
// W1 fragments (+1-deep h ping-pong), fully unrolled (static indices), under
// launch_bounds(512,3) so the ring fits. Outstanding bytes/wave: 2KB -> 8KB.
// Also: h1s rows padded to 520 bf16 (1040B stride -> conflict-free writes
// AND b128 reads; XOR swizzle dropped). Stagger reverted (r4: -3%).
// ---------------------------------------------------------------------------
__launch_bounds__(512, 3)
__global__ void grandag_main(const __bf16* __restrict__ xb,
                             const __bf16* __restrict__ W0p,
                             const __bf16* __restrict__ W1p,
                             const float* __restrict__ W2,
                             float* __restrict__ out) {
    __shared__ __bf16 h1s[NT * PLD2];    // 66560 B
    __shared__ float  outp2[8][NT];      // 2048 B: per-wave partials (no atomics)
    __shared__ float  w2s[HH];           // 2048 B: W2[d] staged by global_load_lds

    const int b  = blockIdx.x;
    // XCD swizzle: d % 8 == blockIdx % 8 -> all 32 tiles of a d on one XCD
    const int d  = ((b >> 8) << 3) | (b & 7);
    const int n0 = ((b >> 3) & 31) * NT;

    const int tid = threadIdx.x;
    const int wq  = __builtin_amdgcn_readfirstlane(tid >> 6);  // wave id (SGPR)
    const int l   = tid & 63;
    const int lr  = l & 31;     // C/D col = batch row within 32-tile
    const int lh  = l >> 5;     // k half-group

    const int kz  = d >> 4;          // k-step containing column d of X
    const int lhz = (d >> 3) & 1;    // half-group containing it
    const int jz  = d & 7;           // element containing it

    // W2[d] -> LDS: waves 0,1 each DMA 1KB (16B/lane). Drained by the
    // phase-1 barrier's vmcnt(0); consumed in phase 3.
    if (wq < 2) {
        const float* g = W2 + (size_t)d * HH + (size_t)(wq * 64 + l) * 4;
        __builtin_amdgcn_global_load_lds((as1cv)g, (as3v)(w2s + wq * 256), 16, 0, 0);
    }

    // ---- phase 1: acc[mt][nt] = W0[d]^T (32-col tiles) . Xmask^T (32-row tiles)
    {
        floatx16 acc[2][2] = {};
        const __bf16* W0b = W0p + ((size_t)(d * 16 + wq * 2) * 8) * 512 + (size_t)l * 8;
        const __bf16* xbb = xb + (size_t)(n0 + lr) * DD + lh * 8;

        // depth-2 ring on W0 frags (8 iters total)
        bf16x8 wbuf[2][2];
#pragma unroll
        for (int s = 0; s < 2; s++) {
            wbuf[s][0] = *(const bf16x8*)(W0b + (size_t)s * 512);
            wbuf[s][1] = *(const bf16x8*)(W0b + (size_t)(8 + s) * 512);
        }
#pragma unroll
        for (int ks = 0; ks < 8; ks++) {
            const int s = ks & 1;
            bf16x8 w0 = wbuf[s][0], w1 = wbuf[s][1];
            if (ks + 2 < 8) {
                wbuf[s][0] = *(const bf16x8*)(W0b + (size_t)(ks + 2) * 512);
                wbuf[s][1] = *(const bf16x8*)(W0b + (size_t)(8 + ks + 2) * 512);
            }
            bf16x8 x0 = *(const bf16x8*)(xbb + (size_t)ks * 16);
            bf16x8 x1 = *(const bf16x8*)(xbb + (size_t)(32 * DD) + ks * 16);
            if (ks == kz && lh == lhz) {
#pragma unroll
                for (int j = 0; j < 8; j++)
                    if (j == jz) { x0[j] = (__bf16)0.f; x1[j] = (__bf16)0.f; }
            }
            acc[0][0] = __builtin_amdgcn_mfma_f32_32x32x16_bf16(w0, x0, acc[0][0], 0, 0, 0);
            acc[0][1] = __builtin_amdgcn_mfma_f32_32x32x16_bf16(w0, x1, acc[0][1], 0, 0, 0);
            acc[1][0] = __builtin_amdgcn_mfma_f32_32x32x16_bf16(w1, x0, acc[1][0], 0, 0, 0);
            acc[1][1] = __builtin_amdgcn_mfma_f32_32x32x16_bf16(w1, x1, acc[1][1], 0, 0, 0);
        }
        // epilogue: lane holds h1[row = nt*32+lr][hcol = 64wq+32mt+8q2+4lh+i]
        // h1s: row-major, padded stride PLD2 (no swizzle needed).
#pragma unroll
        for (int mt = 0; mt < 2; mt++) {
#pragma unroll
            for (int q2 = 0; q2 < 4; q2++) {
                const int chunk = 8 * wq + 4 * mt + q2;   // 8-elem group index
#pragma unroll
                for (int nt = 0; nt < 2; nt++) {
                    const int row = nt * 32 + lr;
                    bf16x4 o;
#pragma unroll
                    for (int i = 0; i < 4; i++) {
                        float v = acc[mt][nt][q2 * 4 + i];
                        o[i] = (__bf16)fmaxf(v, 0.01f * v);   // leaky relu
                    }
                    *(bf16x4*)(h1s + (size_t)row * PLD2 + chunk * 8 + lh * 4) = o;
                }
            }
        }
    }
    __syncthreads();

    // ---- phase 2: acc2[mt][nt] = W1[d]^T (32-col tiles) . h1^T (32-row tiles)
    // 4-slot W-fragment register ring + 1-deep h ping-pong, fully unrolled.
    floatx16 acc2[2][2] = {};
    {
        const __bf16* W1b  = W1p + ((size_t)(d * 16 + wq * 2) * 32) * 512 + (size_t)l * 8;
        const __bf16* h1b0 = h1s + (size_t)lr * PLD2;          // nt=0 row
        const __bf16* h1b1 = h1s + (size_t)(32 + lr) * PLD2;   // nt=1 row

        bf16x8 wbuf[4][2];
#pragma unroll
        for (int s = 0; s < 4; s++) {
            wbuf[s][0] = *(const bf16x8*)(W1b + (size_t)s * 512);
            wbuf[s][1] = *(const bf16x8*)(W1b + (size_t)(32 + s) * 512);
        }
        bf16x8 h0  = *(const bf16x8*)(h1b0 + lh * 8);
        bf16x8 h1v = *(const bf16x8*)(h1b1 + lh * 8);
#pragma unroll
        for (int i = 0; i < 32; i++) {
            const int s = i & 3;
            bf16x8 w0 = wbuf[s][0], w1 = wbuf[s][1];
            if (i + 4 < 32) {   // reissue slot for iter i+4
                wbuf[s][0] = *(const bf16x8*)(W1b + (size_t)(i + 4) * 512);
                wbuf[s][1] = *(const bf16x8*)(W1b + (size_t)(32 + i + 4) * 512);
            }
            bf16x8 hc0 = h0, hc1 = h1v;
            if (i + 1 < 32) {   // prefetch next h frags
                h0  = *(const bf16x8*)(h1b0 + (2 * (i + 1) + lh) * 8);
                h1v = *(const bf16x8*)(h1b1 + (2 * (i + 1) + lh) * 8);
            }
            acc2[0][0] = __builtin_amdgcn_mfma_f32_32x32x16_bf16(w0, hc0, acc2[0][0], 0, 0, 0);
            acc2[0][1] = __builtin_amdgcn_mfma_f32_32x32x16_bf16(w0, hc1, acc2[0][1], 0, 0, 0);
            acc2[1][0] = __builtin_amdgcn_mfma_f32_32x32x16_bf16(w1, hc0, acc2[1][0], 0, 0, 0);
            acc2[1][1] = __builtin_amdgcn_mfma_f32_32x32x16_bf16(w1, hc1, acc2[1][1], 0, 0, 0);
        }
    }

    // ---- phase 3: out = leaky(h2) @ W2[d] (from LDS); lane lr holds rows nt*32+lr
    {
        const float* W2b = w2s + wq * 64 + lh * 4;
#pragma unroll
        for (int nt = 0; nt < 2; nt++) {
            float s = 0.f;
#pragma unroll
            for (int mt = 0; mt < 2; mt++) {
#pragma unroll
                for (int q2 = 0; q2 < 4; q2++) {
                    floatx4 w2q = *(const floatx4*)(W2b + mt * 32 + 8 * q2);
#pragma unroll
                    for (int i = 0; i < 4; i++) {
                        float v = acc2[mt][nt][q2 * 4 + i];
                        s += fmaxf(v, 0.01f * v) * w2q[i];
                    }
                }
            }
            // the lh=1 half holds the other 32 h-cols of this wave
            s += __shfl_xor(s, 32, 64);
            if (!lh) outp2[wq][nt * 32 + lr] = s;   // per-wave partial, no atomics
        }
    }
    __syncthreads();
    if (tid < NT) {
        float v = 0.f;
#pragma unroll
        for (int ww = 0; ww < 8; ww++) v += outp2[ww][tid];
        out[(size_t)(n0 + tid) * DD + d] = v;
    }
}

// ---------------------------------------------------------------------------
extern "C" void kernel_launch(void* const* d_in, const int* in_sizes, int n_in,
                              void* d_out, int out_size, void* d_ws, size_t ws_size,
                              hipStream_t stream) {
    const float* x  = (const float*)d_in[0];
    const float* W0 = (const float*)d_in[1];
    const float* W1 = (const float*)d_in[2];
    const float* W2 = (const float*)d_in[3];
    float* out = (float*)d_out;

    __bf16* W0p = (__bf16*)d_ws;                                          // 16.8 MB
    __bf16* W1p = (__bf16*)((char*)d_ws + (size_t)DD * DD * HH * 2);      // 67.1 MB
    __bf16* xb  = (__bf16*)((char*)d_ws + (size_t)DD * DD * HH * 2
                                        + (size_t)DD * HH * HH * 2);      // 0.5 MB

    cvt_x<<<dim3(NN * DD / (256 * 4)), 256, 0, stream>>>(x, xb);
    pack_w<<<dim3(DD * (DD / 32)), 256, 0, stream>>>(W0, W0p, DD / 32);   // 512 blocks
    pack_w<<<dim3(DD * (HH / 32)), 256, 0, stream>>>(W1, W1p, HH / 32);   // 2048 blocks

    grandag_main<<<dim3(DD * (NN / NT)), 512, 0, stream>>>(xb, W0p, W1p, W2, out);
}